// Round 1
// baseline (365.816 us; speedup 1.0000x reference)
//
#include <hip/hip_runtime.h>

// CompositeValueNoise: out[i] = sum over levels res in {16,32,64,128} of
//   mult(res) * trilinear_smoothstep(V_res, x[i]),  mult = 16/res.
// One thread per point. 8 float4 corner gathers per level (fields contiguous).

__device__ __forceinline__ float4 lerp4(float4 a, float4 b, float w) {
    return make_float4(a.x + w * (b.x - a.x),
                       a.y + w * (b.y - a.y),
                       a.z + w * (b.z - a.z),
                       a.w + w * (b.w - a.w));
}

template <int RES>
__device__ __forceinline__ float4 level_val(const float4* __restrict__ V,
                                            float px, float py, float pz) {
    constexpr int S = RES + 1;
    // Mirror reference: xs = fmod(x*res, res); fl = floor; t = xs - fl.
    float xs = fmodf(px * (float)RES, (float)RES);
    float ys = fmodf(py * (float)RES, (float)RES);
    float zs = fmodf(pz * (float)RES, (float)RES);
    float fx = floorf(xs), fy = floorf(ys), fz = floorf(zs);
    float tx = xs - fx, ty = ys - fy, tz = zs - fz;
    int ix = (int)fx, iy = (int)fy, iz = (int)fz;  // in [0, RES-1]; +1 reaches RES (grid has RES+1)

    float wx = (3.0f - 2.0f * tx) * tx * tx;
    float wy = (3.0f - 2.0f * ty) * ty * ty;
    float wz = (3.0f - 2.0f * tz) * tz * tz;

    int base = (ix * S + iy) * S + iz;      // in float4 units (4 fields per grid node)
    const float4* p0 = V + base;            // plane ix
    const float4* p1 = p0 + S * S;          // plane ix+1

    float4 c000 = p0[0];
    float4 c001 = p0[1];
    float4 c010 = p0[S];
    float4 c011 = p0[S + 1];
    float4 c100 = p1[0];
    float4 c101 = p1[1];
    float4 c110 = p1[S];
    float4 c111 = p1[S + 1];

    // Reference lerps dim 0 (x) first, then y, then z.
    float4 m00 = lerp4(c000, c100, wx);
    float4 m01 = lerp4(c001, c101, wx);
    float4 m10 = lerp4(c010, c110, wx);
    float4 m11 = lerp4(c011, c111, wx);
    float4 n0  = lerp4(m00, m10, wy);
    float4 n1  = lerp4(m01, m11, wy);
    return lerp4(n0, n1, wz);
}

__global__ void __launch_bounds__(256)
CompositeValueNoise_43662637531393_kernel(const float* __restrict__ x,
                                          const float4* __restrict__ V16,
                                          const float4* __restrict__ V32,
                                          const float4* __restrict__ V64,
                                          const float4* __restrict__ V128,
                                          float4* __restrict__ out,
                                          int n) {
    int i = blockIdx.x * blockDim.x + threadIdx.x;
    if (i >= n) return;

    float px = x[3 * i + 0];
    float py = x[3 * i + 1];
    float pz = x[3 * i + 2];

    float4 acc = level_val<16>(V16, px, py, pz);            // mult = 1
    float4 v;

    v = level_val<32>(V32, px, py, pz);                     // mult = 0.5
    acc.x += 0.5f * v.x; acc.y += 0.5f * v.y; acc.z += 0.5f * v.z; acc.w += 0.5f * v.w;

    v = level_val<64>(V64, px, py, pz);                     // mult = 0.25
    acc.x += 0.25f * v.x; acc.y += 0.25f * v.y; acc.z += 0.25f * v.z; acc.w += 0.25f * v.w;

    v = level_val<128>(V128, px, py, pz);                   // mult = 0.125
    acc.x += 0.125f * v.x; acc.y += 0.125f * v.y; acc.z += 0.125f * v.z; acc.w += 0.125f * v.w;

    out[i] = acc;
}

extern "C" void kernel_launch(void* const* d_in, const int* in_sizes, int n_in,
                              void* d_out, int out_size, void* d_ws, size_t ws_size,
                              hipStream_t stream) {
    const float*  x    = (const float*)d_in[0];
    const float4* V16  = (const float4*)d_in[1];
    const float4* V32  = (const float4*)d_in[2];
    const float4* V64  = (const float4*)d_in[3];
    const float4* V128 = (const float4*)d_in[4];
    float4* out = (float4*)d_out;

    int n = in_sizes[0] / 3;  // N_POINTS
    int block = 256;
    int grid = (n + block - 1) / block;
    CompositeValueNoise_43662637531393_kernel<<<grid, block, 0, stream>>>(
        x, V16, V32, V64, V128, out, n);
}